// Round 4
// baseline (203.918 us; speedup 1.0000x reference)
//
#include <hip/hip_runtime.h>

// ---------------------------------------------------------------------------
// QueryInteractionModuleGroup2 — round 3:
//  * swapped-QK^T max-free attention (lane-local softmax, exp2 domain)
//  * 128/64-tile BK=64 swizzled-LDS GEMM with prefetch, fused QKV launch
// N=4096, D=256, H=8, HD=32, FF=1024, groups=4
// ---------------------------------------------------------------------------

typedef __attribute__((ext_vector_type(8))) __bf16 bf16x8;
typedef __attribute__((ext_vector_type(4))) float f32x4;

#define NSPLIT 2

static __device__ __forceinline__ unsigned short f2bf(float f) {
    union { float f; unsigned u; } v; v.f = f;
    unsigned r = v.u + 0x7fffu + ((v.u >> 16) & 1u);
    return (unsigned short)(r >> 16);
}

// ---------------------------------------------------------------------------
// Deterministic stable counting sort by group id (4 groups), single block.
// ---------------------------------------------------------------------------
__global__ __launch_bounds__(256) void k_sort(
    const int* __restrict__ gid, int N,
    int* __restrict__ perm, int* __restrict__ rank,
    int* __restrict__ gid_s, int* __restrict__ offs)
{
    __shared__ int cnt[256][4];
    __shared__ int base[4];
    int t = threadIdx.x;
    int per = N / 256;
    int c[4] = {0, 0, 0, 0};
    for (int i = 0; i < per; ++i) c[gid[t * per + i] & 3]++;
    for (int g = 0; g < 4; ++g) cnt[t][g] = c[g];
    __syncthreads();
    for (int off = 1; off < 256; off <<= 1) {
        int v[4] = {0, 0, 0, 0};
        if (t >= off) for (int g = 0; g < 4; ++g) v[g] = cnt[t - off][g];
        __syncthreads();
        if (t >= off) for (int g = 0; g < 4; ++g) cnt[t][g] += v[g];
        __syncthreads();
    }
    if (t == 0) {
        base[0] = 0;
        base[1] = cnt[255][0];
        base[2] = base[1] + cnt[255][1];
        base[3] = base[2] + cnt[255][2];
        offs[0] = 0; offs[1] = base[1]; offs[2] = base[2]; offs[3] = base[3]; offs[4] = N;
    }
    __syncthreads();
    int run[4];
    for (int g = 0; g < 4; ++g) run[g] = base[g] + (t ? cnt[t - 1][g] : 0);
    for (int i = 0; i < per; ++i) {
        int n = t * per + i;
        int g = gid[n] & 3;
        int p = run[g]++;
        perm[p] = n; rank[n] = p; gid_s[p] = g;
    }
}

// ---------------------------------------------------------------------------
// Prep (writes into SORTED row space via rank[])
// ---------------------------------------------------------------------------
__global__ __launch_bounds__(256) void k_prep(
    const float* __restrict__ ref_pts, const float* __restrict__ pred_boxes,
    const float* __restrict__ scores, const float* __restrict__ embed,
    const int* __restrict__ rank,
    unsigned short* __restrict__ qk_bf, unsigned short* __restrict__ emb_bf)
{
    int n = blockIdx.x, d = threadIdx.x;
    int pos = rank[n];
    bool ip = scores[n] > 0.5f;
    int c = d >> 6, k = (d >> 1) & 31, s = d & 1;
    float p = (ip ? pred_boxes : ref_pts)[n * 4 + c] * 6.283185307179586f;
    float freq = exp2f(-(float)k * (13.287712379549449f / 32.0f));
    float ang = p * freq;
    float e = s ? cosf(ang) : sinf(ang);
    float em = embed[(size_t)n * 256 + d];
    qk_bf[(size_t)pos * 256 + d] = f2bf(e + em);
    emb_bf[(size_t)pos * 256 + d] = f2bf(em);
}

// ---------------------------------------------------------------------------
// Weight conversion f32 -> bf16
// ---------------------------------------------------------------------------
__global__ __launch_bounds__(256) void k_convw(
    const float* __restrict__ w0, const float* __restrict__ w1,
    const float* __restrict__ w2, const float* __restrict__ w3,
    const float* __restrict__ w4, const float* __restrict__ w5,
    unsigned short* __restrict__ o0, unsigned short* __restrict__ o1,
    unsigned short* __restrict__ o2, unsigned short* __restrict__ o3,
    unsigned short* __restrict__ o4, unsigned short* __restrict__ o5)
{
    long i = ((long)blockIdx.x * 256 + threadIdx.x) * 4;
    const float* src; unsigned short* dst; long off;
    if      (i <  196608) { src = w0; dst = o0; off = i; }
    else if (i <  262144) { src = w1; dst = o1; off = i -  196608; }
    else if (i <  524288) { src = w2; dst = o2; off = i -  262144; }
    else if (i <  786432) { src = w3; dst = o3; off = i -  524288; }
    else if (i < 1048576) { src = w4; dst = o4; off = i -  786432; }
    else                  { src = w5; dst = o5; off = i - 1048576; }
    float4 v = *(const float4*)(src + off);
    ushort4 o; o.x = f2bf(v.x); o.y = f2bf(v.y); o.z = f2bf(v.z); o.w = f2bf(v.w);
    *(ushort4*)(dst + off) = o;
}

// ---------------------------------------------------------------------------
// GEMM: C[M x Nout] = A[M x K](bf16) @ B[Nout x K](bf16)^T + bias, epilogues.
// BM x BN tile, 4 waves (2x2), BK=64, XOR-swizzled LDS, reg-prefetch.
// EPI_QKV: cols<512 -> QKbuf (Q scaled by log2e/sqrt32); cols>=512 -> Vt^T.
// ---------------------------------------------------------------------------
#define EPI_QKV     0
#define EPI_RESF32  2
#define EPI_RELUBF  3

template<int BM, int BN, int EPI>
__global__ __launch_bounds__(256) void k_gemm(
    const unsigned short* __restrict__ A, const unsigned short* __restrict__ A2,
    const unsigned short* __restrict__ B,
    const float* __restrict__ bias, const float* __restrict__ resid,
    const int* __restrict__ perm,
    void* __restrict__ out, void* __restrict__ out2,
    int M, int Nout, int K)
{
    constexpr int AIT = BM / 32;   // uint4 staging iters for A (256 thr)
    constexpr int BIT = BN / 32;
    constexpr int MI = BM / 32;    // 16-row frags per wave (wave tile = BM/2)
    constexpr int NJ = BN / 32;
    __shared__ __align__(16) char smem[(BM + BN) * 128];
    char* AsB = smem;
    char* BsB = smem + BM * 128;

    int mt = M / BM;
    int bm = blockIdx.x % mt, bn = blockIdx.x / mt;
    int m0 = bm * BM, c0 = bn * BN;
    int tid = threadIdx.x;
    int wave = tid >> 6, lane = tid & 63;
    int wr = wave >> 1, wc = wave & 1;
    int g = lane >> 4, r15 = lane & 15;

    const unsigned short* Asrc = A;
    if constexpr (EPI == EPI_QKV) { if (c0 >= 512) Asrc = A2; }

    int arow[AIT], au[AIT], brow[BIT], bu[BIT];
    #pragma unroll
    for (int i = 0; i < AIT; ++i) { int idx = tid + i * 256; arow[i] = idx >> 3; au[i] = idx & 7; }
    #pragma unroll
    for (int i = 0; i < BIT; ++i) { int idx = tid + i * 256; brow[i] = idx >> 3; bu[i] = idx & 7; }

    uint4 va[AIT], vb[BIT];
    #pragma unroll
    for (int i = 0; i < AIT; ++i)
        va[i] = *(const uint4*)(Asrc + (size_t)(m0 + arow[i]) * K + au[i] * 8);
    #pragma unroll
    for (int i = 0; i < BIT; ++i)
        vb[i] = *(const uint4*)(B + (size_t)(c0 + brow[i]) * K + bu[i] * 8);

    f32x4 acc[MI][NJ] = {};

    for (int kk0 = 0; kk0 < K; kk0 += 64) {
        #pragma unroll
        for (int i = 0; i < AIT; ++i)
            *(uint4*)(AsB + arow[i] * 128 + ((au[i] ^ (arow[i] & 7)) << 4)) = va[i];
        #pragma unroll
        for (int i = 0; i < BIT; ++i)
            *(uint4*)(BsB + brow[i] * 128 + ((bu[i] ^ (brow[i] & 7)) << 4)) = vb[i];
        __syncthreads();
        if (kk0 + 64 < K) {
            #pragma unroll
            for (int i = 0; i < AIT; ++i)
                va[i] = *(const uint4*)(Asrc + (size_t)(m0 + arow[i]) * K + kk0 + 64 + au[i] * 8);
            #pragma unroll
            for (int i = 0; i < BIT; ++i)
                vb[i] = *(const uint4*)(B + (size_t)(c0 + brow[i]) * K + kk0 + 64 + bu[i] * 8);
        }
        #pragma unroll
        for (int kk = 0; kk < 2; ++kk) {
            bf16x8 af[MI], bfr[NJ];
            int swz = ((kk * 4 + g) ^ (r15 & 7)) << 4;
            #pragma unroll
            for (int ti = 0; ti < MI; ++ti) {
                int row = wr * (BM / 2) + ti * 16 + r15;
                af[ti] = *(const bf16x8*)(AsB + row * 128 + swz);
            }
            #pragma unroll
            for (int tj = 0; tj < NJ; ++tj) {
                int row = wc * (BN / 2) + tj * 16 + r15;
                bfr[tj] = *(const bf16x8*)(BsB + row * 128 + swz);
            }
            #pragma unroll
            for (int ti = 0; ti < MI; ++ti)
                #pragma unroll
                for (int tj = 0; tj < NJ; ++tj)
                    acc[ti][tj] = __builtin_amdgcn_mfma_f32_16x16x32_bf16(af[ti], bfr[tj], acc[ti][tj], 0, 0, 0);
        }
        __syncthreads();
    }

    #pragma unroll
    for (int ti = 0; ti < MI; ++ti)
    #pragma unroll
    for (int tj = 0; tj < NJ; ++tj)
    #pragma unroll
    for (int r = 0; r < 4; ++r) {
        int n = m0 + wr * (BM / 2) + ti * 16 + g * 4 + r;
        int o = c0 + wc * (BN / 2) + tj * 16 + r15;
        float v = acc[ti][tj][r] + bias[o];
        if constexpr (EPI == EPI_QKV) {
            if (o < 512) {
                // Q pre-scaled by 1/sqrt(32) * log2(e): softmax in exp2 domain
                float s = (o < 256) ? (0.17677669529663687f * 1.4426950408889634f) : 1.0f;
                ((unsigned short*)out)[(size_t)n * 512 + o] = f2bf(v * s);
            } else {
                ((unsigned short*)out2)[(size_t)(o - 512) * M + n] = f2bf(v);
            }
        } else if constexpr (EPI == EPI_RESF32) {
            int rn = perm ? perm[n] : n;
            ((float*)out)[(size_t)n * Nout + o] = v + resid[(size_t)rn * Nout + o];
        } else {
            ((unsigned short*)out)[(size_t)n * Nout + o] = f2bf(fmaxf(v, 0.0f));
        }
    }
}

// ---------------------------------------------------------------------------
// Group-sorted masked flash attention, swapped QK^T, max-free exp2 softmax.
// S^T = mfma(K_frag, Q_frag): lane (g=lane>>4, q=lane&15) holds
//   S[key = t_*16 + g*4 + r][q] -> softmax is lane-local, l-reduce deferred.
// Writes UNNORMALIZED partials Opart + l sums; k_comb divides.
// grid = (N/64) * H * NSPLIT ; block = 256 (4 waves x 16 query rows)
// ---------------------------------------------------------------------------
__global__ __launch_bounds__(256) void k_attn(
    const unsigned short* __restrict__ QK, const unsigned short* __restrict__ Vt,
    const int* __restrict__ gid_s, const int* __restrict__ offs,
    float* __restrict__ Opart, float* __restrict__ lpart, int N)
{
    __shared__ __align__(16) unsigned short Ks[2][64][40];
    __shared__ __align__(16) unsigned short Vs[2][32][72];
    __shared__ __align__(16) unsigned short Ps[4][16][64];  // XOR-swizzled
    __shared__ __align__(16) int gks[2][64];

    int qtiles = N >> 6;
    int bid = blockIdx.x;
    int qt = bid % qtiles;
    int hs = bid / qtiles;
    int h = hs & 7;
    int sp = hs >> 3;
    int q0 = qt * 64;
    int tid = threadIdx.x, wave = tid >> 6, lane = tid & 63;
    int g = lane >> 4, r15 = lane & 15;
    int n0 = q0 + wave * 16;

    int g_lo = gid_s[q0], g_hi = gid_s[q0 + 63];
    int tlo = offs[g_lo] >> 6;
    int thi = (offs[g_hi + 1] + 63) >> 6;
    int ntiles = thi - tlo;
    int chunk = (ntiles + NSPLIT - 1) / NSPLIT;
    int t0 = tlo + sp * chunk;
    int t1 = min(t0 + chunk, thi);

    if (t0 >= t1) {
        #pragma unroll
        for (int r = 0; r < 4; ++r) {
            int n = n0 + g * 4 + r;
            Opart[((size_t)sp * N + n) * 256 + h * 32 + r15] = 0.f;
            Opart[((size_t)sp * N + n) * 256 + h * 32 + 16 + r15] = 0.f;
        }
        if (g == 0) lpart[((size_t)sp * N + n0 + r15) * 8 + h] = 0.f;
        return;
    }

    bf16x8 qf = *(const bf16x8*)(QK + (size_t)(n0 + r15) * 512 + h * 32 + g * 8);
    int gq = gid_s[n0 + r15];

    int kr_ = tid >> 2, kc_ = (tid & 3) * 8;
    int vd_ = tid >> 3, vc_ = (tid & 7) * 8;

    f32x4 O0 = {}, O1 = {};
    float lloc = 0.f;
    unsigned short* PsW = &Ps[wave][0][0];

    {   // prologue: stage tile t0 into buffer 0
        int m0 = t0 << 6;
        *(uint4*)(&Ks[0][kr_][kc_]) = *(const uint4*)(QK + (size_t)(m0 + kr_) * 512 + 256 + h * 32 + kc_);
        *(uint4*)(&Vs[0][vd_][vc_]) = *(const uint4*)(Vt + (size_t)(h * 32 + vd_) * N + m0 + vc_);
        if (tid < 64) gks[0][tid] = gid_s[m0 + tid];
    }
    __syncthreads();

    int cur = 0;
    for (int t = t0; t < t1; ++t) {
        bool more = (t + 1 < t1);
        uint4 kn, vn; int gn = 0;
        if (more) {
            int m0n = (t + 1) << 6;
            kn = *(const uint4*)(QK + (size_t)(m0n + kr_) * 512 + 256 + h * 32 + kc_);
            vn = *(const uint4*)(Vt + (size_t)(h * 32 + vd_) * N + m0n + vc_);
            if (tid < 64) gn = gid_s[m0n + tid];
        }

        // S^T: key = t_*16 + g*4 + r, query = n0 + r15
        f32x4 S[4];
        #pragma unroll
        for (int t_ = 0; t_ < 4; ++t_) {
            bf16x8 kf = *(const bf16x8*)(&Ks[cur][t_ * 16 + r15][g * 8]);
            f32x4 z = {};
            S[t_] = __builtin_amdgcn_mfma_f32_16x16x32_bf16(kf, qf, z, 0, 0, 0);
        }
        // masked exp2 (m=0 fixed: logits are O(5), no overflow), pack P
        #pragma unroll
        for (int t_ = 0; t_ < 4; ++t_) {
            int4 g4 = *(const int4*)(&gks[cur][t_ * 16 + g * 4]);
            float p0 = (g4.x == gq) ? exp2f(S[t_][0]) : 0.f;
            float p1 = (g4.y == gq) ? exp2f(S[t_][1]) : 0.f;
            float p2 = (g4.z == gq) ? exp2f(S[t_][2]) : 0.f;
            float p3 = (g4.w == gq) ? exp2f(S[t_][3]) : 0.f;
            lloc += (p0 + p1) + (p2 + p3);
            ushort4 pw;
            pw.x = f2bf(p0); pw.y = f2bf(p1); pw.z = f2bf(p2); pw.w = f2bf(p3);
            int off = t_ * 32 + g * 8;
            int byte = r15 * 128 + ((((off >> 4) ^ (r15 & 7)) << 4) | (off & 15));
            *(ushort4*)((char*)PsW + byte) = pw;
        }
        // PV: A = P[16q x 64k] (per-wave LDS, same-wave ordered), B = V^T
        #pragma unroll
        for (int kk = 0; kk < 2; ++kk) {
            int byte = r15 * 128 + (((kk * 4 + g) ^ (r15 & 7)) << 4);
            bf16x8 pf = *(const bf16x8*)((char*)PsW + byte);
            bf16x8 v0 = *(const bf16x8*)(&Vs[cur][r15][kk * 32 + g * 8]);
            bf16x8 v1 = *(const bf16x8*)(&Vs[cur][16 + r15][kk * 32 + g * 8]);
            O0 = __builtin_amdgcn_mfma_f32_16x16x32_bf16(pf, v0, O0, 0, 0, 0);
            O1 = __builtin_amdgcn_mfma_f32_16x16x32_bf16(pf, v1, O1, 0, 0, 0);
        }

        if (more) {
            *(uint4*)(&Ks[cur ^ 1][kr_][kc_]) = kn;
            *(uint4*)(&Vs[cur ^ 1][vd_][vc_]) = vn;
            if (tid < 64) gks[cur ^ 1][tid] = gn;
        }
        __syncthreads();
        cur ^= 1;
    }

    // one-time l reduction: across the 4 g-lane groups sharing q = r15
    float l = lloc;
    l += __shfl_xor(l, 16, 64);
    l += __shfl_xor(l, 32, 64);
    if (g == 0) lpart[((size_t)sp * N + n0 + r15) * 8 + h] = l;

    #pragma unroll
    for (int r = 0; r < 4; ++r) {
        int n = n0 + g * 4 + r;
        Opart[((size_t)sp * N + n) * 256 + h * 32 + r15]      = O0[r];
        Opart[((size_t)sp * N + n) * 256 + h * 32 + 16 + r15] = O1[r];
    }
}

// ---------------------------------------------------------------------------
// Combine key-split partials -> ctx bf16. grid = N, block = 256.
// ---------------------------------------------------------------------------
__global__ __launch_bounds__(256) void k_comb(
    const float* __restrict__ Opart, const float* __restrict__ lpart,
    unsigned short* __restrict__ ctx, int N)
{
    int n = blockIdx.x, d = threadIdx.x;
    int h = d >> 5;
    float l0 = lpart[((size_t)n) * 8 + h];
    float l1 = lpart[((size_t)N + n) * 8 + h];
    float inv = 1.0f / (l0 + l1);
    float o = Opart[(size_t)n * 256 + d] + Opart[((size_t)N + n) * 256 + d];
    ctx[(size_t)n * 256 + d] = f2bf(o * inv);
}

// ---------------------------------------------------------------------------
// LayerNorm over 256 cols; 4 waves/block.
// ---------------------------------------------------------------------------
template<int MODE>
__global__ __launch_bounds__(256) void k_ln(
    const float* __restrict__ y, const float* __restrict__ w, const float* __restrict__ b,
    float* __restrict__ of32, unsigned short* __restrict__ obf,
    const float* __restrict__ scores, const float* __restrict__ qpos,
    const int* __restrict__ perm)
{
    int wave = threadIdx.x >> 6, lane = threadIdx.x & 63;
    int row = blockIdx.x * 4 + wave;
    const float4 x = *(const float4*)(y + (size_t)row * 256 + lane * 4);
    float s = x.x + x.y + x.z + x.w;
    #pragma unroll
    for (int off = 1; off < 64; off <<= 1) s += __shfl_xor(s, off, 64);
    float mean = s * (1.0f / 256.0f);
    float d0 = x.x - mean, d1 = x.y - mean, d2 = x.z - mean, d3 = x.w - mean;
    float q = d0 * d0 + d1 * d1 + d2 * d2 + d3 * d3;
    #pragma unroll
    for (int off = 1; off < 64; off <<= 1) q += __shfl_xor(q, off, 64);
    float rs = rsqrtf(q * (1.0f / 256.0f) + 1e-5f);
    const float4 wv = *(const float4*)(w + lane * 4);
    const float4 bv = *(const float4*)(b + lane * 4);
    float o0 = d0 * rs * wv.x + bv.x;
    float o1 = d1 * rs * wv.y + bv.y;
    float o2 = d2 * rs * wv.z + bv.z;
    float o3 = d3 * rs * wv.w + bv.w;
    if constexpr (MODE == 0) {
        *(float4*)(of32 + (size_t)row * 256 + lane * 4) = make_float4(o0, o1, o2, o3);
        ushort4 ob; ob.x = f2bf(o0); ob.y = f2bf(o1); ob.z = f2bf(o2); ob.w = f2bf(o3);
        *(ushort4*)(obf + (size_t)row * 256 + lane * 4) = ob;
    } else if constexpr (MODE == 1) {
        ushort4 ob; ob.x = f2bf(o0); ob.y = f2bf(o1); ob.z = f2bf(o2); ob.w = f2bf(o3);
        *(ushort4*)(obf + (size_t)row * 256 + lane * 4) = ob;
    } else {
        int n = perm[row];
        bool ip = scores[n] > 0.5f;
        const float4 qp = *(const float4*)(qpos + (size_t)n * 256 + lane * 4);
        float4 ov = ip ? make_float4(o0, o1, o2, o3) : qp;
        *(float4*)(of32 + (size_t)n * 256 + lane * 4) = ov;
    }
}

// ---------------------------------------------------------------------------
extern "C" void kernel_launch(void* const* d_in, const int* in_sizes, int n_in,
                              void* d_out, int out_size, void* d_ws, size_t ws_size,
                              hipStream_t stream)
{
    const float* ref_pts    = (const float*)d_in[0];
    const float* pred_boxes = (const float*)d_in[1];
    const float* scores     = (const float*)d_in[2];
    const float* out_embed  = (const float*)d_in[3];
    const float* query_pos  = (const float*)d_in[4];
    const int*   group_ids  = (const int*)d_in[5];
    const float* in_proj_w  = (const float*)d_in[7];
    const float* in_proj_b  = (const float*)d_in[8];
    const float* out_proj_w = (const float*)d_in[9];
    const float* out_proj_b = (const float*)d_in[10];
    const float* lin1_w     = (const float*)d_in[11];
    const float* lin1_b     = (const float*)d_in[12];
    const float* lin2_w     = (const float*)d_in[13];
    const float* lin2_b     = (const float*)d_in[14];
    const float* feat1_w    = (const float*)d_in[15];
    const float* feat1_b    = (const float*)d_in[16];
    const float* feat2_w    = (const float*)d_in[17];
    const float* feat2_b    = (const float*)d_in[18];
    const float* norm1_w    = (const float*)d_in[19];
    const float* norm1_b    = (const float*)d_in[20];
    const float* norm2_w    = (const float*)d_in[21];
    const float* norm2_b    = (const float*)d_in[22];
    const float* normf_w    = (const float*)d_in[23];
    const float* normf_b    = (const float*)d_in[24];

    const int N = in_sizes[2];  // 4096

    char* ws = (char*)d_ws;
    size_t off = 0;
    auto alloc = [&](size_t bytes) -> void* {
        void* p = ws + off; off += (bytes + 255) & ~(size_t)255; return p;
    };
    unsigned short* wqkv   = (unsigned short*)alloc((size_t)768 * 256 * 2);
    unsigned short* wout   = (unsigned short*)alloc((size_t)256 * 256 * 2);
    unsigned short* wlin1  = (unsigned short*)alloc((size_t)1024 * 256 * 2);
    unsigned short* wlin2  = (unsigned short*)alloc((size_t)256 * 1024 * 2);
    unsigned short* wfeat1 = (unsigned short*)alloc((size_t)1024 * 256 * 2);
    unsigned short* wfeat2 = (unsigned short*)alloc((size_t)256 * 1024 * 2);
    unsigned short* qk_bf  = (unsigned short*)alloc((size_t)N * 256 * 2);
    unsigned short* emb_bf = (unsigned short*)alloc((size_t)N * 256 * 2);
    unsigned short* QKbuf  = (unsigned short*)alloc((size_t)N * 512 * 2);
    unsigned short* Vtbuf  = (unsigned short*)alloc((size_t)256 * N * 2);
    unsigned short* ctxbuf = (unsigned short*)alloc((size_t)N * 256 * 2);
    float*          ybuf   = (float*)alloc((size_t)N * 256 * 4);
    float*          tgtf   = (float*)alloc((size_t)N * 256 * 4);
    unsigned short* tgtbf  = (unsigned short*)alloc((size_t)N * 256 * 2);
    unsigned short* t2bf   = (unsigned short*)alloc((size_t)N * 256 * 2);
    unsigned short* hbuf   = (unsigned short*)alloc((size_t)N * 1024 * 2);
    int* permbuf = (int*)alloc((size_t)N * 4);
    int* rankbuf = (int*)alloc((size_t)N * 4);
    int* gidsbuf = (int*)alloc((size_t)N * 4);
    int* offsbuf = (int*)alloc(32 * 4);
    float* Opartbuf = (float*)alloc((size_t)NSPLIT * N * 256 * 4);
    float* lbuf     = (float*)alloc((size_t)NSPLIT * N * 8 * 4);
    (void)ws_size; (void)n_in; (void)out_size;

    k_sort<<<1, 256, 0, stream>>>(group_ids, N, permbuf, rankbuf, gidsbuf, offsbuf);
    k_convw<<<1280, 256, 0, stream>>>(in_proj_w, out_proj_w, lin1_w, lin2_w, feat1_w, feat2_w,
                                      wqkv, wout, wlin1, wlin2, wfeat1, wfeat2);
    k_prep<<<N, 256, 0, stream>>>(ref_pts, pred_boxes, scores, out_embed, rankbuf,
                                  qk_bf, emb_bf);

    // fused Q,K,V projection: cols 0..511 from qk_bf -> QKbuf; 512..767 from emb_bf -> Vt^T
    k_gemm<128, 128, EPI_QKV><<<(N / 128) * 6, 256, 0, stream>>>(
        qk_bf, emb_bf, wqkv, in_proj_b, nullptr, nullptr, QKbuf, Vtbuf, N, 768, 256);

    k_attn<<<(N / 64) * 8 * NSPLIT, 256, 0, stream>>>(QKbuf, Vtbuf, gidsbuf, offsbuf,
                                                      Opartbuf, lbuf, N);
    k_comb<<<N, 256, 0, stream>>>(Opartbuf, lbuf, ctxbuf, N);

    k_gemm<64, 64, EPI_RESF32><<<(N / 64) * 4, 256, 0, stream>>>(
        ctxbuf, nullptr, wout, out_proj_b, out_embed, permbuf, ybuf, nullptr, N, 256, 256);
    k_ln<0><<<N / 4, 256, 0, stream>>>(ybuf, norm1_w, norm1_b, tgtf, tgtbf, nullptr, nullptr, nullptr);

    k_gemm<128, 128, EPI_RELUBF><<<(N / 128) * 8, 256, 0, stream>>>(
        tgtbf, nullptr, wlin1, lin1_b, nullptr, nullptr, hbuf, nullptr, N, 1024, 256);
    k_gemm<64, 64, EPI_RESF32><<<(N / 64) * 4, 256, 0, stream>>>(
        hbuf, nullptr, wlin2, lin2_b, tgtf, nullptr, ybuf, nullptr, N, 256, 1024);
    k_ln<1><<<N / 4, 256, 0, stream>>>(ybuf, norm2_w, norm2_b, nullptr, t2bf, nullptr, nullptr, nullptr);

    k_gemm<128, 128, EPI_RELUBF><<<(N / 128) * 8, 256, 0, stream>>>(
        t2bf, nullptr, wfeat1, feat1_b, nullptr, nullptr, hbuf, nullptr, N, 1024, 256);
    k_gemm<64, 64, EPI_RESF32><<<(N / 64) * 4, 256, 0, stream>>>(
        hbuf, nullptr, wfeat2, feat2_b, query_pos, permbuf, ybuf, nullptr, N, 256, 1024);
    k_ln<2><<<N / 4, 256, 0, stream>>>(ybuf, normf_w, normf_b, (float*)d_out, nullptr,
                                       scores, query_pos, permbuf);
}

// Round 5
// 156.442 us; speedup vs baseline: 1.3035x; 1.3035x over previous
//
#include <hip/hip_runtime.h>

// ---------------------------------------------------------------------------
// QueryInteractionModuleGroup2 — round 4:
//  * keep swapped-QK^T max-free attention (R3 win)
//  * revert GEMM to proven R2 64²-tile version (R3's 128² rewrite regressed)
// N=4096, D=256, H=8, HD=32, FF=1024, groups=4
// ---------------------------------------------------------------------------

typedef __attribute__((ext_vector_type(8))) __bf16 bf16x8;
typedef __attribute__((ext_vector_type(4))) float f32x4;

#define NSPLIT 2

static __device__ __forceinline__ unsigned short f2bf(float f) {
    union { float f; unsigned u; } v; v.f = f;
    unsigned r = v.u + 0x7fffu + ((v.u >> 16) & 1u);
    return (unsigned short)(r >> 16);
}

// ---------------------------------------------------------------------------
// Deterministic stable counting sort by group id (4 groups), single block.
// ---------------------------------------------------------------------------
__global__ __launch_bounds__(256) void k_sort(
    const int* __restrict__ gid, int N,
    int* __restrict__ perm, int* __restrict__ rank,
    int* __restrict__ gid_s, int* __restrict__ offs)
{
    __shared__ int cnt[256][4];
    __shared__ int base[4];
    int t = threadIdx.x;
    int per = N / 256;
    int c[4] = {0, 0, 0, 0};
    for (int i = 0; i < per; ++i) c[gid[t * per + i] & 3]++;
    for (int g = 0; g < 4; ++g) cnt[t][g] = c[g];
    __syncthreads();
    for (int off = 1; off < 256; off <<= 1) {
        int v[4] = {0, 0, 0, 0};
        if (t >= off) for (int g = 0; g < 4; ++g) v[g] = cnt[t - off][g];
        __syncthreads();
        if (t >= off) for (int g = 0; g < 4; ++g) cnt[t][g] += v[g];
        __syncthreads();
    }
    if (t == 0) {
        base[0] = 0;
        base[1] = cnt[255][0];
        base[2] = base[1] + cnt[255][1];
        base[3] = base[2] + cnt[255][2];
        offs[0] = 0; offs[1] = base[1]; offs[2] = base[2]; offs[3] = base[3]; offs[4] = N;
    }
    __syncthreads();
    int run[4];
    for (int g = 0; g < 4; ++g) run[g] = base[g] + (t ? cnt[t - 1][g] : 0);
    for (int i = 0; i < per; ++i) {
        int n = t * per + i;
        int g = gid[n] & 3;
        int p = run[g]++;
        perm[p] = n; rank[n] = p; gid_s[p] = g;
    }
}

// ---------------------------------------------------------------------------
// Prep (writes into SORTED row space via rank[])
// ---------------------------------------------------------------------------
__global__ __launch_bounds__(256) void k_prep(
    const float* __restrict__ ref_pts, const float* __restrict__ pred_boxes,
    const float* __restrict__ scores, const float* __restrict__ embed,
    const int* __restrict__ rank,
    unsigned short* __restrict__ qk_bf, unsigned short* __restrict__ emb_bf)
{
    int n = blockIdx.x, d = threadIdx.x;
    int pos = rank[n];
    bool ip = scores[n] > 0.5f;
    int c = d >> 6, k = (d >> 1) & 31, s = d & 1;
    float p = (ip ? pred_boxes : ref_pts)[n * 4 + c] * 6.283185307179586f;
    float freq = exp2f(-(float)k * (13.287712379549449f / 32.0f));
    float ang = p * freq;
    float e = s ? cosf(ang) : sinf(ang);
    float em = embed[(size_t)n * 256 + d];
    qk_bf[(size_t)pos * 256 + d] = f2bf(e + em);
    emb_bf[(size_t)pos * 256 + d] = f2bf(em);
}

// ---------------------------------------------------------------------------
// Weight conversion f32 -> bf16
// ---------------------------------------------------------------------------
__global__ __launch_bounds__(256) void k_convw(
    const float* __restrict__ w0, const float* __restrict__ w1,
    const float* __restrict__ w2, const float* __restrict__ w3,
    const float* __restrict__ w4, const float* __restrict__ w5,
    unsigned short* __restrict__ o0, unsigned short* __restrict__ o1,
    unsigned short* __restrict__ o2, unsigned short* __restrict__ o3,
    unsigned short* __restrict__ o4, unsigned short* __restrict__ o5)
{
    long i = ((long)blockIdx.x * 256 + threadIdx.x) * 4;
    const float* src; unsigned short* dst; long off;
    if      (i <  196608) { src = w0; dst = o0; off = i; }
    else if (i <  262144) { src = w1; dst = o1; off = i -  196608; }
    else if (i <  524288) { src = w2; dst = o2; off = i -  262144; }
    else if (i <  786432) { src = w3; dst = o3; off = i -  524288; }
    else if (i < 1048576) { src = w4; dst = o4; off = i -  786432; }
    else                  { src = w5; dst = o5; off = i - 1048576; }
    float4 v = *(const float4*)(src + off);
    ushort4 o; o.x = f2bf(v.x); o.y = f2bf(v.y); o.z = f2bf(v.z); o.w = f2bf(v.w);
    *(ushort4*)(dst + off) = o;
}

// ---------------------------------------------------------------------------
// GEMM (R2-proven): C[M x Nout] = A[M x K] @ B[Nout x K]^T + bias, epilogues
// 64x64 tile, 4 waves (2x2 of 32x32), BK=32, [64][40] padded LDS
// ---------------------------------------------------------------------------
#define EPI_QK      0   // scale first 256 cols by log2e/sqrt(32), store bf16
#define EPI_VT      1   // store bf16 transposed: out[o*M + n]
#define EPI_RESF32  2   // out f32 = acc + bias + resid[gather(n)*Nout+o]
#define EPI_RELUBF  3   // out bf16 = relu(acc + bias)

template<int EPI>
__global__ __launch_bounds__(256) void k_gemm(
    const unsigned short* __restrict__ A, const unsigned short* __restrict__ B,
    const float* __restrict__ bias, const float* __restrict__ resid,
    const int* __restrict__ perm,
    void* __restrict__ out, int M, int Nout, int K)
{
    __shared__ __align__(16) unsigned short As[64][40];
    __shared__ __align__(16) unsigned short Bs[64][40];
    int mt = M >> 6;
    int bm = blockIdx.x % mt, bn = blockIdx.x / mt;
    int m0 = bm * 64, c0 = bn * 64;
    int tid = threadIdx.x;
    int wave = tid >> 6, lane = tid & 63;
    int wr = wave >> 1, wc = wave & 1;
    int g = lane >> 4, r15 = lane & 15;
    int srow = tid >> 2, scol = (tid & 3) * 8;

    f32x4 acc[2][2] = {};
    for (int kk = 0; kk < K; kk += 32) {
        *(uint4*)(&As[srow][scol]) = *(const uint4*)(A + (size_t)(m0 + srow) * K + kk + scol);
        *(uint4*)(&Bs[srow][scol]) = *(const uint4*)(B + (size_t)(c0 + srow) * K + kk + scol);
        __syncthreads();
        bf16x8 af0 = *(const bf16x8*)(&As[wr * 32 + r15][g * 8]);
        bf16x8 af1 = *(const bf16x8*)(&As[wr * 32 + 16 + r15][g * 8]);
        bf16x8 bf0 = *(const bf16x8*)(&Bs[wc * 32 + r15][g * 8]);
        bf16x8 bf1 = *(const bf16x8*)(&Bs[wc * 32 + 16 + r15][g * 8]);
        acc[0][0] = __builtin_amdgcn_mfma_f32_16x16x32_bf16(af0, bf0, acc[0][0], 0, 0, 0);
        acc[0][1] = __builtin_amdgcn_mfma_f32_16x16x32_bf16(af0, bf1, acc[0][1], 0, 0, 0);
        acc[1][0] = __builtin_amdgcn_mfma_f32_16x16x32_bf16(af1, bf0, acc[1][0], 0, 0, 0);
        acc[1][1] = __builtin_amdgcn_mfma_f32_16x16x32_bf16(af1, bf1, acc[1][1], 0, 0, 0);
        __syncthreads();
    }
    #pragma unroll
    for (int ti = 0; ti < 2; ++ti)
    #pragma unroll
    for (int tj = 0; tj < 2; ++tj)
    #pragma unroll
    for (int r = 0; r < 4; ++r) {
        int n = m0 + wr * 32 + ti * 16 + g * 4 + r;
        int o = c0 + wc * 32 + tj * 16 + r15;
        float v = acc[ti][tj][r] + bias[o];
        if constexpr (EPI == EPI_QK) {
            // Q pre-scaled by 1/sqrt(32) * log2(e): softmax works in exp2 domain
            float s = (o < 256) ? (0.17677669529663687f * 1.4426950408889634f) : 1.0f;
            ((unsigned short*)out)[(size_t)n * Nout + o] = f2bf(v * s);
        } else if constexpr (EPI == EPI_VT) {
            ((unsigned short*)out)[(size_t)o * M + n] = f2bf(v);
        } else if constexpr (EPI == EPI_RESF32) {
            int rn = perm ? perm[n] : n;
            ((float*)out)[(size_t)n * Nout + o] = v + resid[(size_t)rn * Nout + o];
        } else {
            ((unsigned short*)out)[(size_t)n * Nout + o] = f2bf(fmaxf(v, 0.0f));
        }
    }
}

// ---------------------------------------------------------------------------
// Group-sorted masked flash attention, swapped QK^T, max-free exp2 softmax.
// S^T = mfma(K_frag, Q_frag): lane (g=lane>>4, q=lane&15) holds
//   S[key = t_*16 + g*4 + r][q] -> softmax is lane-local, l-reduce deferred.
// Writes UNNORMALIZED partials Opart + l sums; k_comb divides.
// grid = (N/64) * H * NSPLIT ; block = 256 (4 waves x 16 query rows)
// ---------------------------------------------------------------------------
__global__ __launch_bounds__(256) void k_attn(
    const unsigned short* __restrict__ QK, const unsigned short* __restrict__ Vt,
    const int* __restrict__ gid_s, const int* __restrict__ offs,
    float* __restrict__ Opart, float* __restrict__ lpart, int N)
{
    __shared__ __align__(16) unsigned short Ks[2][64][40];
    __shared__ __align__(16) unsigned short Vs[2][32][72];
    __shared__ __align__(16) unsigned short Ps[4][16][64];  // XOR-swizzled
    __shared__ __align__(16) int gks[2][64];

    int qtiles = N >> 6;
    int bid = blockIdx.x;
    int qt = bid % qtiles;
    int hs = bid / qtiles;
    int h = hs & 7;
    int sp = hs >> 3;
    int q0 = qt * 64;
    int tid = threadIdx.x, wave = tid >> 6, lane = tid & 63;
    int g = lane >> 4, r15 = lane & 15;
    int n0 = q0 + wave * 16;

    int g_lo = gid_s[q0], g_hi = gid_s[q0 + 63];
    int tlo = offs[g_lo] >> 6;
    int thi = (offs[g_hi + 1] + 63) >> 6;
    int ntiles = thi - tlo;
    int chunk = (ntiles + NSPLIT - 1) / NSPLIT;
    int t0 = tlo + sp * chunk;
    int t1 = min(t0 + chunk, thi);

    if (t0 >= t1) {
        #pragma unroll
        for (int r = 0; r < 4; ++r) {
            int n = n0 + g * 4 + r;
            Opart[((size_t)sp * N + n) * 256 + h * 32 + r15] = 0.f;
            Opart[((size_t)sp * N + n) * 256 + h * 32 + 16 + r15] = 0.f;
        }
        if (g == 0) lpart[((size_t)sp * N + n0 + r15) * 8 + h] = 0.f;
        return;
    }

    bf16x8 qf = *(const bf16x8*)(QK + (size_t)(n0 + r15) * 512 + h * 32 + g * 8);
    int gq = gid_s[n0 + r15];

    int kr_ = tid >> 2, kc_ = (tid & 3) * 8;
    int vd_ = tid >> 3, vc_ = (tid & 7) * 8;

    f32x4 O0 = {}, O1 = {};
    float lloc = 0.f;
    unsigned short* PsW = &Ps[wave][0][0];

    {   // prologue: stage tile t0 into buffer 0
        int m0 = t0 << 6;
        *(uint4*)(&Ks[0][kr_][kc_]) = *(const uint4*)(QK + (size_t)(m0 + kr_) * 512 + 256 + h * 32 + kc_);
        *(uint4*)(&Vs[0][vd_][vc_]) = *(const uint4*)(Vt + (size_t)(h * 32 + vd_) * N + m0 + vc_);
        if (tid < 64) gks[0][tid] = gid_s[m0 + tid];
    }
    __syncthreads();

    int cur = 0;
    for (int t = t0; t < t1; ++t) {
        bool more = (t + 1 < t1);
        uint4 kn, vn; int gn = 0;
        if (more) {
            int m0n = (t + 1) << 6;
            kn = *(const uint4*)(QK + (size_t)(m0n + kr_) * 512 + 256 + h * 32 + kc_);
            vn = *(const uint4*)(Vt + (size_t)(h * 32 + vd_) * N + m0n + vc_);
            if (tid < 64) gn = gid_s[m0n + tid];
        }

        // S^T: key = t_*16 + g*4 + r, query = n0 + r15
        f32x4 S[4];
        #pragma unroll
        for (int t_ = 0; t_ < 4; ++t_) {
            bf16x8 kf = *(const bf16x8*)(&Ks[cur][t_ * 16 + r15][g * 8]);
            f32x4 z = {};
            S[t_] = __builtin_amdgcn_mfma_f32_16x16x32_bf16(kf, qf, z, 0, 0, 0);
        }
        // masked exp2 (m=0 fixed: logits are O(5), no overflow), pack P
        #pragma unroll
        for (int t_ = 0; t_ < 4; ++t_) {
            int4 g4 = *(const int4*)(&gks[cur][t_ * 16 + g * 4]);
            float p0 = (g4.x == gq) ? exp2f(S[t_][0]) : 0.f;
            float p1 = (g4.y == gq) ? exp2f(S[t_][1]) : 0.f;
            float p2 = (g4.z == gq) ? exp2f(S[t_][2]) : 0.f;
            float p3 = (g4.w == gq) ? exp2f(S[t_][3]) : 0.f;
            lloc += (p0 + p1) + (p2 + p3);
            ushort4 pw;
            pw.x = f2bf(p0); pw.y = f2bf(p1); pw.z = f2bf(p2); pw.w = f2bf(p3);
            int off = t_ * 32 + g * 8;
            int byte = r15 * 128 + ((((off >> 4) ^ (r15 & 7)) << 4) | (off & 15));
            *(ushort4*)((char*)PsW + byte) = pw;
        }
        // PV: A = P[16q x 64k] (per-wave LDS, same-wave ordered), B = V^T
        #pragma unroll
        for (int kk = 0; kk < 2; ++kk) {
            int byte = r15 * 128 + (((kk * 4 + g) ^ (r15 & 7)) << 4);
            bf16x8 pf = *(const bf16x8*)((char*)PsW + byte);
            bf16x8 v0 = *(const bf16x8*)(&Vs[cur][r15][kk * 32 + g * 8]);
            bf16x8 v1 = *(const bf16x8*)(&Vs[cur][16 + r15][kk * 32 + g * 8]);
            O0 = __builtin_amdgcn_mfma_f32_16x16x32_bf16(pf, v0, O0, 0, 0, 0);
            O1 = __builtin_amdgcn_mfma_f32_16x16x32_bf16(pf, v1, O1, 0, 0, 0);
        }

        if (more) {
            *(uint4*)(&Ks[cur ^ 1][kr_][kc_]) = kn;
            *(uint4*)(&Vs[cur ^ 1][vd_][vc_]) = vn;
            if (tid < 64) gks[cur ^ 1][tid] = gn;
        }
        __syncthreads();
        cur ^= 1;
    }

    // one-time l reduction: across the 4 g-lane groups sharing q = r15
    float l = lloc;
    l += __shfl_xor(l, 16, 64);
    l += __shfl_xor(l, 32, 64);
    if (g == 0) lpart[((size_t)sp * N + n0 + r15) * 8 + h] = l;

    #pragma unroll
    for (int r = 0; r < 4; ++r) {
        int n = n0 + g * 4 + r;
        Opart[((size_t)sp * N + n) * 256 + h * 32 + r15]      = O0[r];
        Opart[((size_t)sp * N + n) * 256 + h * 32 + 16 + r15] = O1[r];
    }
}

// ---------------------------------------------------------------------------
// Combine key-split partials -> ctx bf16. grid = N, block = 256.
// ---------------------------------------------------------------------------
__global__ __launch_bounds__(256) void k_comb(
    const float* __restrict__ Opart, const float* __restrict__ lpart,
    unsigned short* __restrict__ ctx, int N)
{
    int n = blockIdx.x, d = threadIdx.x;
    int h = d >> 5;
    float l0 = lpart[((size_t)n) * 8 + h];
    float l1 = lpart[((size_t)N + n) * 8 + h];
    float inv = 1.0f / (l0 + l1);
    float o = Opart[(size_t)n * 256 + d] + Opart[((size_t)N + n) * 256 + d];
    ctx[(size_t)n * 256 + d] = f2bf(o * inv);
}

// ---------------------------------------------------------------------------
// LayerNorm over 256 cols; 4 waves/block.
// ---------------------------------------------------------------------------
template<int MODE>
__global__ __launch_bounds__(256) void k_ln(
    const float* __restrict__ y, const float* __restrict__ w, const float* __restrict__ b,
    float* __restrict__ of32, unsigned short* __restrict__ obf,
    const float* __restrict__ scores, const float* __restrict__ qpos,
    const int* __restrict__ perm)
{
    int wave = threadIdx.x >> 6, lane = threadIdx.x & 63;
    int row = blockIdx.x * 4 + wave;
    const float4 x = *(const float4*)(y + (size_t)row * 256 + lane * 4);
    float s = x.x + x.y + x.z + x.w;
    #pragma unroll
    for (int off = 1; off < 64; off <<= 1) s += __shfl_xor(s, off, 64);
    float mean = s * (1.0f / 256.0f);
    float d0 = x.x - mean, d1 = x.y - mean, d2 = x.z - mean, d3 = x.w - mean;
    float q = d0 * d0 + d1 * d1 + d2 * d2 + d3 * d3;
    #pragma unroll
    for (int off = 1; off < 64; off <<= 1) q += __shfl_xor(q, off, 64);
    float rs = rsqrtf(q * (1.0f / 256.0f) + 1e-5f);
    const float4 wv = *(const float4*)(w + lane * 4);
    const float4 bv = *(const float4*)(b + lane * 4);
    float o0 = d0 * rs * wv.x + bv.x;
    float o1 = d1 * rs * wv.y + bv.y;
    float o2 = d2 * rs * wv.z + bv.z;
    float o3 = d3 * rs * wv.w + bv.w;
    if constexpr (MODE == 0) {
        *(float4*)(of32 + (size_t)row * 256 + lane * 4) = make_float4(o0, o1, o2, o3);
        ushort4 ob; ob.x = f2bf(o0); ob.y = f2bf(o1); ob.z = f2bf(o2); ob.w = f2bf(o3);
        *(ushort4*)(obf + (size_t)row * 256 + lane * 4) = ob;
    } else if constexpr (MODE == 1) {
        ushort4 ob; ob.x = f2bf(o0); ob.y = f2bf(o1); ob.z = f2bf(o2); ob.w = f2bf(o3);
        *(ushort4*)(obf + (size_t)row * 256 + lane * 4) = ob;
    } else {
        int n = perm[row];
        bool ip = scores[n] > 0.5f;
        const float4 qp = *(const float4*)(qpos + (size_t)n * 256 + lane * 4);
        float4 ov = ip ? make_float4(o0, o1, o2, o3) : qp;
        *(float4*)(of32 + (size_t)n * 256 + lane * 4) = ov;
    }
}

// ---------------------------------------------------------------------------
extern "C" void kernel_launch(void* const* d_in, const int* in_sizes, int n_in,
                              void* d_out, int out_size, void* d_ws, size_t ws_size,
                              hipStream_t stream)
{
    const float* ref_pts    = (const float*)d_in[0];
    const float* pred_boxes = (const float*)d_in[1];
    const float* scores     = (const float*)d_in[2];
    const float* out_embed  = (const float*)d_in[3];
    const float* query_pos  = (const float*)d_in[4];
    const int*   group_ids  = (const int*)d_in[5];
    const float* in_proj_w  = (const float*)d_in[7];
    const float* in_proj_b  = (const float*)d_in[8];
    const float* out_proj_w = (const float*)d_in[9];
    const float* out_proj_b = (const float*)d_in[10];
    const float* lin1_w     = (const float*)d_in[11];
    const float* lin1_b     = (const float*)d_in[12];
    const float* lin2_w     = (const float*)d_in[13];
    const float* lin2_b     = (const float*)d_in[14];
    const float* feat1_w    = (const float*)d_in[15];
    const float* feat1_b    = (const float*)d_in[16];
    const float* feat2_w    = (const float*)d_in[17];
    const float* feat2_b    = (const float*)d_in[18];
    const float* norm1_w    = (const float*)d_in[19];
    const float* norm1_b    = (const float*)d_in[20];
    const float* norm2_w    = (const float*)d_in[21];
    const float* norm2_b    = (const float*)d_in[22];
    const float* normf_w    = (const float*)d_in[23];
    const float* normf_b    = (const float*)d_in[24];

    const int N = in_sizes[2];  // 4096

    char* ws = (char*)d_ws;
    size_t off = 0;
    auto alloc = [&](size_t bytes) -> void* {
        void* p = ws + off; off += (bytes + 255) & ~(size_t)255; return p;
    };
    unsigned short* wqkv   = (unsigned short*)alloc((size_t)768 * 256 * 2);
    unsigned short* wout   = (unsigned short*)alloc((size_t)256 * 256 * 2);
    unsigned short* wlin1  = (unsigned short*)alloc((size_t)1024 * 256 * 2);
    unsigned short* wlin2  = (unsigned short*)alloc((size_t)256 * 1024 * 2);
    unsigned short* wfeat1 = (unsigned short*)alloc((size_t)1024 * 256 * 2);
    unsigned short* wfeat2 = (unsigned short*)alloc((size_t)256 * 1024 * 2);
    unsigned short* qk_bf  = (unsigned short*)alloc((size_t)N * 256 * 2);
    unsigned short* emb_bf = (unsigned short*)alloc((size_t)N * 256 * 2);
    unsigned short* QKbuf  = (unsigned short*)alloc((size_t)N * 512 * 2);
    unsigned short* Vtbuf  = (unsigned short*)alloc((size_t)256 * N * 2);
    unsigned short* ctxbuf = (unsigned short*)alloc((size_t)N * 256 * 2);
    float*          ybuf   = (float*)alloc((size_t)N * 256 * 4);
    float*          tgtf   = (float*)alloc((size_t)N * 256 * 4);
    unsigned short* tgtbf  = (unsigned short*)alloc((size_t)N * 256 * 2);
    unsigned short* t2bf   = (unsigned short*)alloc((size_t)N * 256 * 2);
    unsigned short* hbuf   = (unsigned short*)alloc((size_t)N * 1024 * 2);
    int* permbuf = (int*)alloc((size_t)N * 4);
    int* rankbuf = (int*)alloc((size_t)N * 4);
    int* gidsbuf = (int*)alloc((size_t)N * 4);
    int* offsbuf = (int*)alloc(32 * 4);
    float* Opartbuf = (float*)alloc((size_t)NSPLIT * N * 256 * 4);
    float* lbuf     = (float*)alloc((size_t)NSPLIT * N * 8 * 4);
    (void)ws_size; (void)n_in; (void)out_size;

    const int mt = N >> 6;

    k_sort<<<1, 256, 0, stream>>>(group_ids, N, permbuf, rankbuf, gidsbuf, offsbuf);
    k_convw<<<1280, 256, 0, stream>>>(in_proj_w, out_proj_w, lin1_w, lin2_w, feat1_w, feat2_w,
                                      wqkv, wout, wlin1, wlin2, wfeat1, wfeat2);
    k_prep<<<N, 256, 0, stream>>>(ref_pts, pred_boxes, scores, out_embed, rankbuf,
                                  qk_bf, emb_bf);

    // QK projection (Nout=512, Q pre-scaled by log2e/sqrt(32))
    k_gemm<EPI_QK><<<mt * 8, 256, 0, stream>>>(qk_bf, wqkv, in_proj_b, nullptr, nullptr,
                                               QKbuf, N, 512, 256);
    // V projection, written transposed [256][N]
    k_gemm<EPI_VT><<<mt * 4, 256, 0, stream>>>(emb_bf, wqkv + (size_t)512 * 256, in_proj_b + 512,
                                               nullptr, nullptr, Vtbuf, N, 256, 256);
    // key-split swapped-QK^T flash attention + combine
    k_attn<<<mt * 8 * NSPLIT, 256, 0, stream>>>(QKbuf, Vtbuf, gidsbuf, offsbuf,
                                                Opartbuf, lbuf, N);
    k_comb<<<N, 256, 0, stream>>>(Opartbuf, lbuf, ctxbuf, N);

    k_gemm<EPI_RESF32><<<mt * 4, 256, 0, stream>>>(ctxbuf, wout, out_proj_b, out_embed, permbuf,
                                                   ybuf, N, 256, 256);
    k_ln<0><<<N / 4, 256, 0, stream>>>(ybuf, norm1_w, norm1_b, tgtf, tgtbf, nullptr, nullptr, nullptr);
    k_gemm<EPI_RELUBF><<<mt * 16, 256, 0, stream>>>(tgtbf, wlin1, lin1_b, nullptr, nullptr,
                                                    hbuf, N, 1024, 256);
    k_gemm<EPI_RESF32><<<mt * 4, 256, 0, stream>>>(hbuf, wlin2, lin2_b, tgtf, nullptr,
                                                   ybuf, N, 256, 1024);
    k_ln<1><<<N / 4, 256, 0, stream>>>(ybuf, norm2_w, norm2_b, nullptr, t2bf, nullptr, nullptr, nullptr);
    k_gemm<EPI_RELUBF><<<mt * 16, 256, 0, stream>>>(t2bf, wfeat1, feat1_b, nullptr, nullptr,
                                                    hbuf, N, 1024, 256);
    k_gemm<EPI_RESF32><<<mt * 4, 256, 0, stream>>>(hbuf, wfeat2, feat2_b, query_pos, permbuf,
                                                   ybuf, N, 256, 1024);
    k_ln<2><<<N / 4, 256, 0, stream>>>(ybuf, normf_w, normf_b, (float*)d_out, nullptr,
                                       scores, query_pos, permbuf);
}

// Round 6
// 123.094 us; speedup vs baseline: 1.6566x; 1.2709x over previous
//
#include <hip/hip_runtime.h>

// ---------------------------------------------------------------------------
// QueryInteractionModuleGroup2 — round 5:
//  * GEMM: BK=64, double-buffered LDS, reg prefetch, 1 barrier/K-step
//  * fused QKV projection launch; sorted f32 residuals (coalesced epilogues)
//  * keep swapped-QK^T max-free attention (proven)
// N=4096, D=256, H=8, HD=32, FF=1024, groups=4
// ---------------------------------------------------------------------------

typedef __attribute__((ext_vector_type(8))) __bf16 bf16x8;
typedef __attribute__((ext_vector_type(4))) float f32x4;

#define NSPLIT 2

static __device__ __forceinline__ unsigned short f2bf(float f) {
    union { float f; unsigned u; } v; v.f = f;
    unsigned r = v.u + 0x7fffu + ((v.u >> 16) & 1u);
    return (unsigned short)(r >> 16);
}

// ---------------------------------------------------------------------------
// Deterministic stable counting sort by group id (4 groups), single block.
// ---------------------------------------------------------------------------
__global__ __launch_bounds__(1024) void k_sort(
    const int* __restrict__ gid, int N,
    int* __restrict__ perm, int* __restrict__ rank,
    int* __restrict__ gid_s, int* __restrict__ offs)
{
    __shared__ int cnt[1024][4];
    __shared__ int base[4];
    int t = threadIdx.x;
    int per = N / 1024;
    int c[4] = {0, 0, 0, 0};
    for (int i = 0; i < per; ++i) c[gid[t * per + i] & 3]++;
    for (int g = 0; g < 4; ++g) cnt[t][g] = c[g];
    __syncthreads();
    for (int off = 1; off < 1024; off <<= 1) {
        int v[4] = {0, 0, 0, 0};
        if (t >= off) for (int g = 0; g < 4; ++g) v[g] = cnt[t - off][g];
        __syncthreads();
        if (t >= off) for (int g = 0; g < 4; ++g) cnt[t][g] += v[g];
        __syncthreads();
    }
    if (t == 0) {
        base[0] = 0;
        base[1] = cnt[1023][0];
        base[2] = base[1] + cnt[1023][1];
        base[3] = base[2] + cnt[1023][2];
        offs[0] = 0; offs[1] = base[1]; offs[2] = base[2]; offs[3] = base[3]; offs[4] = N;
    }
    __syncthreads();
    int run[4];
    for (int g = 0; g < 4; ++g) run[g] = base[g] + (t ? cnt[t - 1][g] : 0);
    for (int i = 0; i < per; ++i) {
        int n = t * per + i;
        int g = gid[n] & 3;
        int p = run[g]++;
        perm[p] = n; rank[n] = p; gid_s[p] = g;
    }
}

// ---------------------------------------------------------------------------
// Prep (writes into SORTED row space via rank[]):
// qk = pos2posemb(ref)+embed (bf16), emb bf16, emb f32 copy, query_pos f32 copy
// ---------------------------------------------------------------------------
__global__ __launch_bounds__(256) void k_prep(
    const float* __restrict__ ref_pts, const float* __restrict__ pred_boxes,
    const float* __restrict__ scores, const float* __restrict__ embed,
    const float* __restrict__ qpos, const int* __restrict__ rank,
    unsigned short* __restrict__ qk_bf, unsigned short* __restrict__ emb_bf,
    float* __restrict__ emb_f32s, float* __restrict__ qpos_s)
{
    int n = blockIdx.x, d = threadIdx.x;
    int pos = rank[n];
    bool ip = scores[n] > 0.5f;
    int c = d >> 6, k = (d >> 1) & 31, s = d & 1;
    float p = (ip ? pred_boxes : ref_pts)[n * 4 + c] * 6.283185307179586f;
    float freq = exp2f(-(float)k * (13.287712379549449f / 32.0f));
    float ang = p * freq;
    float e = s ? cosf(ang) : sinf(ang);
    float em = embed[(size_t)n * 256 + d];
    qk_bf[(size_t)pos * 256 + d] = f2bf(e + em);
    emb_bf[(size_t)pos * 256 + d] = f2bf(em);
    emb_f32s[(size_t)pos * 256 + d] = em;
    qpos_s[(size_t)pos * 256 + d] = qpos[(size_t)n * 256 + d];
}

// ---------------------------------------------------------------------------
// Weight conversion f32 -> bf16
// ---------------------------------------------------------------------------
__global__ __launch_bounds__(256) void k_convw(
    const float* __restrict__ w0, const float* __restrict__ w1,
    const float* __restrict__ w2, const float* __restrict__ w3,
    const float* __restrict__ w4, const float* __restrict__ w5,
    unsigned short* __restrict__ o0, unsigned short* __restrict__ o1,
    unsigned short* __restrict__ o2, unsigned short* __restrict__ o3,
    unsigned short* __restrict__ o4, unsigned short* __restrict__ o5)
{
    long i = ((long)blockIdx.x * 256 + threadIdx.x) * 4;
    const float* src; unsigned short* dst; long off;
    if      (i <  196608) { src = w0; dst = o0; off = i; }
    else if (i <  262144) { src = w1; dst = o1; off = i -  196608; }
    else if (i <  524288) { src = w2; dst = o2; off = i -  262144; }
    else if (i <  786432) { src = w3; dst = o3; off = i -  524288; }
    else if (i < 1048576) { src = w4; dst = o4; off = i -  786432; }
    else                  { src = w5; dst = o5; off = i - 1048576; }
    float4 v = *(const float4*)(src + off);
    ushort4 o; o.x = f2bf(v.x); o.y = f2bf(v.y); o.z = f2bf(v.z); o.w = f2bf(v.w);
    *(ushort4*)(dst + off) = o;
}

// ---------------------------------------------------------------------------
// GEMM: C[M x Nout] = A[M x K](bf16) @ B[Nout x K](bf16)^T + bias, epilogues.
// 64x64 tile, 4 waves (2x2 of 32x32), BK=64, double-buffered [64][72] LDS,
// register prefetch, ONE barrier per K-step.
// EPI_QKV: c0<512 -> QKbuf (Q scaled log2e/sqrt32); c0>=512 -> Vt transposed.
// ---------------------------------------------------------------------------
#define EPI_QKV     0
#define EPI_RESF32  2   // out f32 = acc + bias + resid[n*Nout+o]  (sorted, coalesced)
#define EPI_RELUBF  3   // out bf16 = relu(acc + bias)

template<int EPI>
__global__ __launch_bounds__(256) void k_gemm(
    const unsigned short* __restrict__ A, const unsigned short* __restrict__ A2,
    const unsigned short* __restrict__ B,
    const float* __restrict__ bias, const float* __restrict__ resid,
    void* __restrict__ out, void* __restrict__ out2,
    int M, int Nout, int K)
{
    __shared__ __align__(16) unsigned short As[2][64][72];
    __shared__ __align__(16) unsigned short Bs[2][64][72];
    int mt = M >> 6;
    int bm = blockIdx.x % mt, bn = blockIdx.x / mt;
    int m0 = bm * 64, c0 = bn * 64;
    int tid = threadIdx.x;
    int wave = tid >> 6, lane = tid & 63;
    int wr = wave >> 1, wc = wave & 1;
    int g = lane >> 4, r15 = lane & 15;

    const unsigned short* Asrc = A;
    if constexpr (EPI == EPI_QKV) { if (c0 >= 512) Asrc = A2; }

    // staging: 512 uint4 slots per matrix per K-tile; 2 per thread
    int r0 = tid >> 3, u0 = tid & 7;
    int r1 = (tid + 256) >> 3, u1 = tid & 7;  // (tid+256)&7 == tid&7

    const unsigned short* Abase = Asrc + (size_t)m0 * K;
    const unsigned short* Bbase = B + (size_t)c0 * K;

    uint4 a0 = *(const uint4*)(Abase + (size_t)r0 * K + u0 * 8);
    uint4 a1 = *(const uint4*)(Abase + (size_t)r1 * K + u1 * 8);
    uint4 b0 = *(const uint4*)(Bbase + (size_t)r0 * K + u0 * 8);
    uint4 b1 = *(const uint4*)(Bbase + (size_t)r1 * K + u1 * 8);
    *(uint4*)(&As[0][r0][u0 * 8]) = a0;
    *(uint4*)(&As[0][r1][u1 * 8]) = a1;
    *(uint4*)(&Bs[0][r0][u0 * 8]) = b0;
    *(uint4*)(&Bs[0][r1][u1 * 8]) = b1;
    __syncthreads();

    f32x4 acc[2][2] = {};
    int nk = K >> 6;
    for (int kt = 0; kt < nk; ++kt) {
        int cur = kt & 1;
        bool more = (kt + 1 < nk);
        if (more) {
            int kc = (kt + 1) << 6;
            a0 = *(const uint4*)(Abase + (size_t)r0 * K + kc + u0 * 8);
            a1 = *(const uint4*)(Abase + (size_t)r1 * K + kc + u1 * 8);
            b0 = *(const uint4*)(Bbase + (size_t)r0 * K + kc + u0 * 8);
            b1 = *(const uint4*)(Bbase + (size_t)r1 * K + kc + u1 * 8);
        }
        #pragma unroll
        for (int kk = 0; kk < 2; ++kk) {
            bf16x8 af0 = *(const bf16x8*)(&As[cur][wr * 32 + r15][kk * 32 + g * 8]);
            bf16x8 af1 = *(const bf16x8*)(&As[cur][wr * 32 + 16 + r15][kk * 32 + g * 8]);
            bf16x8 bf0 = *(const bf16x8*)(&Bs[cur][wc * 32 + r15][kk * 32 + g * 8]);
            bf16x8 bf1 = *(const bf16x8*)(&Bs[cur][wc * 32 + 16 + r15][kk * 32 + g * 8]);
            acc[0][0] = __builtin_amdgcn_mfma_f32_16x16x32_bf16(af0, bf0, acc[0][0], 0, 0, 0);
            acc[0][1] = __builtin_amdgcn_mfma_f32_16x16x32_bf16(af0, bf1, acc[0][1], 0, 0, 0);
            acc[1][0] = __builtin_amdgcn_mfma_f32_16x16x32_bf16(af1, bf0, acc[1][0], 0, 0, 0);
            acc[1][1] = __builtin_amdgcn_mfma_f32_16x16x32_bf16(af1, bf1, acc[1][1], 0, 0, 0);
        }
        if (more) {
            // writes target the idle buffer: no read/write overlap, 1 barrier
            *(uint4*)(&As[cur ^ 1][r0][u0 * 8]) = a0;
            *(uint4*)(&As[cur ^ 1][r1][u1 * 8]) = a1;
            *(uint4*)(&Bs[cur ^ 1][r0][u0 * 8]) = b0;
            *(uint4*)(&Bs[cur ^ 1][r1][u1 * 8]) = b1;
            __syncthreads();
        }
    }

    #pragma unroll
    for (int ti = 0; ti < 2; ++ti)
    #pragma unroll
    for (int tj = 0; tj < 2; ++tj)
    #pragma unroll
    for (int r = 0; r < 4; ++r) {
        int n = m0 + wr * 32 + ti * 16 + g * 4 + r;
        int o = c0 + wc * 32 + tj * 16 + r15;
        float v = acc[ti][tj][r] + bias[o];
        if constexpr (EPI == EPI_QKV) {
            if (o < 512) {
                // Q pre-scaled by 1/sqrt(32) * log2(e): softmax in exp2 domain
                float s = (o < 256) ? (0.17677669529663687f * 1.4426950408889634f) : 1.0f;
                ((unsigned short*)out)[(size_t)n * 512 + o] = f2bf(v * s);
            } else {
                ((unsigned short*)out2)[(size_t)(o - 512) * M + n] = f2bf(v);
            }
        } else if constexpr (EPI == EPI_RESF32) {
            ((float*)out)[(size_t)n * Nout + o] = v + resid[(size_t)n * Nout + o];
        } else {
            ((unsigned short*)out)[(size_t)n * Nout + o] = f2bf(fmaxf(v, 0.0f));
        }
    }
}

// ---------------------------------------------------------------------------
// Group-sorted masked flash attention, swapped QK^T, max-free exp2 softmax.
// (unchanged from R4 — proven)
// ---------------------------------------------------------------------------
__global__ __launch_bounds__(256) void k_attn(
    const unsigned short* __restrict__ QK, const unsigned short* __restrict__ Vt,
    const int* __restrict__ gid_s, const int* __restrict__ offs,
    float* __restrict__ Opart, float* __restrict__ lpart, int N)
{
    __shared__ __align__(16) unsigned short Ks[2][64][40];
    __shared__ __align__(16) unsigned short Vs[2][32][72];
    __shared__ __align__(16) unsigned short Ps[4][16][64];  // XOR-swizzled
    __shared__ __align__(16) int gks[2][64];

    int qtiles = N >> 6;
    int bid = blockIdx.x;
    int qt = bid % qtiles;
    int hs = bid / qtiles;
    int h = hs & 7;
    int sp = hs >> 3;
    int q0 = qt * 64;
    int tid = threadIdx.x, wave = tid >> 6, lane = tid & 63;
    int g = lane >> 4, r15 = lane & 15;
    int n0 = q0 + wave * 16;

    int g_lo = gid_s[q0], g_hi = gid_s[q0 + 63];
    int tlo = offs[g_lo] >> 6;
    int thi = (offs[g_hi + 1] + 63) >> 6;
    int ntiles = thi - tlo;
    int chunk = (ntiles + NSPLIT - 1) / NSPLIT;
    int t0 = tlo + sp * chunk;
    int t1 = min(t0 + chunk, thi);

    if (t0 >= t1) {
        #pragma unroll
        for (int r = 0; r < 4; ++r) {
            int n = n0 + g * 4 + r;
            Opart[((size_t)sp * N + n) * 256 + h * 32 + r15] = 0.f;
            Opart[((size_t)sp * N + n) * 256 + h * 32 + 16 + r15] = 0.f;
        }
        if (g == 0) lpart[((size_t)sp * N + n0 + r15) * 8 + h] = 0.f;
        return;
    }

    bf16x8 qf = *(const bf16x8*)(QK + (size_t)(n0 + r15) * 512 + h * 32 + g * 8);
    int gq = gid_s[n0 + r15];

    int kr_ = tid >> 2, kc_ = (tid & 3) * 8;
    int vd_ = tid >> 3, vc_ = (tid & 7) * 8;

    f32x4 O0 = {}, O1 = {};
    float lloc = 0.f;
    unsigned short* PsW = &Ps[wave][0][0];

    {   // prologue: stage tile t0 into buffer 0
        int m0 = t0 << 6;
        *(uint4*)(&Ks[0][kr_][kc_]) = *(const uint4*)(QK + (size_t)(m0 + kr_) * 512 + 256 + h * 32 + kc_);
        *(uint4*)(&Vs[0][vd_][vc_]) = *(const uint4*)(Vt + (size_t)(h * 32 + vd_) * N + m0 + vc_);
        if (tid < 64) gks[0][tid] = gid_s[m0 + tid];
    }
    __syncthreads();

    int cur = 0;
    for (int t = t0; t < t1; ++t) {
        bool more = (t + 1 < t1);
        uint4 kn, vn; int gn = 0;
        if (more) {
            int m0n = (t + 1) << 6;
            kn = *(const uint4*)(QK + (size_t)(m0n + kr_) * 512 + 256 + h * 32 + kc_);
            vn = *(const uint4*)(Vt + (size_t)(h * 32 + vd_) * N + m0n + vc_);
            if (tid < 64) gn = gid_s[m0n + tid];
        }

        // S^T: key = t_*16 + g*4 + r, query = n0 + r15
        f32x4 S[4];
        #pragma unroll
        for (int t_ = 0; t_ < 4; ++t_) {
            bf16x8 kf = *(const bf16x8*)(&Ks[cur][t_ * 16 + r15][g * 8]);
            f32x4 z = {};
            S[t_] = __builtin_amdgcn_mfma_f32_16x16x32_bf16(kf, qf, z, 0, 0, 0);
        }
        // masked exp2 (m=0 fixed: logits are O(5), no overflow), pack P
        #pragma unroll
        for (int t_ = 0; t_ < 4; ++t_) {
            int4 g4 = *(const int4*)(&gks[cur][t_ * 16 + g * 4]);
            float p0 = (g4.x == gq) ? exp2f(S[t_][0]) : 0.f;
            float p1 = (g4.y == gq) ? exp2f(S[t_][1]) : 0.f;
            float p2 = (g4.z == gq) ? exp2f(S[t_][2]) : 0.f;
            float p3 = (g4.w == gq) ? exp2f(S[t_][3]) : 0.f;
            lloc += (p0 + p1) + (p2 + p3);
            ushort4 pw;
            pw.x = f2bf(p0); pw.y = f2bf(p1); pw.z = f2bf(p2); pw.w = f2bf(p3);
            int off = t_ * 32 + g * 8;
            int byte = r15 * 128 + ((((off >> 4) ^ (r15 & 7)) << 4) | (off & 15));
            *(ushort4*)((char*)PsW + byte) = pw;
        }
        // PV: A = P[16q x 64k] (per-wave LDS, same-wave ordered), B = V^T
        #pragma unroll
        for (int kk = 0; kk < 2; ++kk) {
            int byte = r15 * 128 + (((kk * 4 + g) ^ (r15 & 7)) << 4);
            bf16x8 pf = *(const bf16x8*)((char*)PsW + byte);
            bf16x8 v0 = *(const bf16x8*)(&Vs[cur][r15][kk * 32 + g * 8]);
            bf16x8 v1 = *(const bf16x8*)(&Vs[cur][16 + r15][kk * 32 + g * 8]);
            O0 = __builtin_amdgcn_mfma_f32_16x16x32_bf16(pf, v0, O0, 0, 0, 0);
            O1 = __builtin_amdgcn_mfma_f32_16x16x32_bf16(pf, v1, O1, 0, 0, 0);
        }

        if (more) {
            *(uint4*)(&Ks[cur ^ 1][kr_][kc_]) = kn;
            *(uint4*)(&Vs[cur ^ 1][vd_][vc_]) = vn;
            if (tid < 64) gks[cur ^ 1][tid] = gn;
        }
        __syncthreads();
        cur ^= 1;
    }

    // one-time l reduction: across the 4 g-lane groups sharing q = r15
    float l = lloc;
    l += __shfl_xor(l, 16, 64);
    l += __shfl_xor(l, 32, 64);
    if (g == 0) lpart[((size_t)sp * N + n0 + r15) * 8 + h] = l;

    #pragma unroll
    for (int r = 0; r < 4; ++r) {
        int n = n0 + g * 4 + r;
        Opart[((size_t)sp * N + n) * 256 + h * 32 + r15]      = O0[r];
        Opart[((size_t)sp * N + n) * 256 + h * 32 + 16 + r15] = O1[r];
    }
}

// ---------------------------------------------------------------------------
// Combine key-split partials -> ctx bf16. grid = N, block = 256.
// ---------------------------------------------------------------------------
__global__ __launch_bounds__(256) void k_comb(
    const float* __restrict__ Opart, const float* __restrict__ lpart,
    unsigned short* __restrict__ ctx, int N)
{
    int n = blockIdx.x, d = threadIdx.x;
    int h = d >> 5;
    float l0 = lpart[((size_t)n) * 8 + h];
    float l1 = lpart[((size_t)N + n) * 8 + h];
    float inv = 1.0f / (l0 + l1);
    float o = Opart[(size_t)n * 256 + d] + Opart[((size_t)N + n) * 256 + d];
    ctx[(size_t)n * 256 + d] = f2bf(o * inv);
}

// ---------------------------------------------------------------------------
// LayerNorm over 256 cols; 4 waves/block.
// MODE 0: f32+bf16 ; MODE 1: bf16 ; MODE 2: select + scatter to d_out
// ---------------------------------------------------------------------------
template<int MODE>
__global__ __launch_bounds__(256) void k_ln(
    const float* __restrict__ y, const float* __restrict__ w, const float* __restrict__ b,
    float* __restrict__ of32, unsigned short* __restrict__ obf,
    const float* __restrict__ scores, const float* __restrict__ qpos_s,
    const int* __restrict__ perm)
{
    int wave = threadIdx.x >> 6, lane = threadIdx.x & 63;
    int row = blockIdx.x * 4 + wave;
    const float4 x = *(const float4*)(y + (size_t)row * 256 + lane * 4);
    float s = x.x + x.y + x.z + x.w;
    #pragma unroll
    for (int off = 1; off < 64; off <<= 1) s += __shfl_xor(s, off, 64);
    float mean = s * (1.0f / 256.0f);
    float d0 = x.x - mean, d1 = x.y - mean, d2 = x.z - mean, d3 = x.w - mean;
    float q = d0 * d0 + d1 * d1 + d2 * d2 + d3 * d3;
    #pragma unroll
    for (int off = 1; off < 64; off <<= 1) q += __shfl_xor(q, off, 64);
    float rs = rsqrtf(q * (1.0f / 256.0f) + 1e-5f);
    const float4 wv = *(const float4*)(w + lane * 4);
    const float4 bv = *(const float4*)(b + lane * 4);
    float o0 = d0 * rs * wv.x + bv.x;
    float o1 = d1 * rs * wv.y + bv.y;
    float o2 = d2 * rs * wv.z + bv.z;
    float o3 = d3 * rs * wv.w + bv.w;
    if constexpr (MODE == 0) {
        *(float4*)(of32 + (size_t)row * 256 + lane * 4) = make_float4(o0, o1, o2, o3);
        ushort4 ob; ob.x = f2bf(o0); ob.y = f2bf(o1); ob.z = f2bf(o2); ob.w = f2bf(o3);
        *(ushort4*)(obf + (size_t)row * 256 + lane * 4) = ob;
    } else if constexpr (MODE == 1) {
        ushort4 ob; ob.x = f2bf(o0); ob.y = f2bf(o1); ob.z = f2bf(o2); ob.w = f2bf(o3);
        *(ushort4*)(obf + (size_t)row * 256 + lane * 4) = ob;
    } else {
        int n = perm[row];
        bool ip = scores[n] > 0.5f;
        const float4 qp = *(const float4*)(qpos_s + (size_t)row * 256 + lane * 4);
        float4 ov = ip ? make_float4(o0, o1, o2, o3) : qp;
        *(float4*)(of32 + (size_t)n * 256 + lane * 4) = ov;
    }
}

// ---------------------------------------------------------------------------
extern "C" void kernel_launch(void* const* d_in, const int* in_sizes, int n_in,
                              void* d_out, int out_size, void* d_ws, size_t ws_size,
                              hipStream_t stream)
{
    const float* ref_pts    = (const float*)d_in[0];
    const float* pred_boxes = (const float*)d_in[1];
    const float* scores     = (const float*)d_in[2];
    const float* out_embed  = (const float*)d_in[3];
    const float* query_pos  = (const float*)d_in[4];
    const int*   group_ids  = (const int*)d_in[5];
    const float* in_proj_w  = (const float*)d_in[7];
    const float* in_proj_b  = (const float*)d_in[8];
    const float* out_proj_w = (const float*)d_in[9];
    const float* out_proj_b = (const float*)d_in[10];
    const float* lin1_w     = (const float*)d_in[11];
    const float* lin1_b     = (const float*)d_in[12];
    const float* lin2_w     = (const float*)d_in[13];
    const float* lin2_b     = (const float*)d_in[14];
    const float* feat1_w    = (const float*)d_in[15];
    const float* feat1_b    = (const float*)d_in[16];
    const float* feat2_w    = (const float*)d_in[17];
    const float* feat2_b    = (const float*)d_in[18];
    const float* norm1_w    = (const float*)d_in[19];
    const float* norm1_b    = (const float*)d_in[20];
    const float* norm2_w    = (const float*)d_in[21];
    const float* norm2_b    = (const float*)d_in[22];
    const float* normf_w    = (const float*)d_in[23];
    const float* normf_b    = (const float*)d_in[24];

    const int N = in_sizes[2];  // 4096

    char* ws = (char*)d_ws;
    size_t off = 0;
    auto alloc = [&](size_t bytes) -> void* {
        void* p = ws + off; off += (bytes + 255) & ~(size_t)255; return p;
    };
    unsigned short* wqkv   = (unsigned short*)alloc((size_t)768 * 256 * 2);
    unsigned short* wout   = (unsigned short*)alloc((size_t)256 * 256 * 2);
    unsigned short* wlin1  = (unsigned short*)alloc((size_t)1024 * 256 * 2);
    unsigned short* wlin2  = (unsigned short*)alloc((size_t)256 * 1024 * 2);
    unsigned short* wfeat1 = (unsigned short*)alloc((size_t)1024 * 256 * 2);
    unsigned short* wfeat2 = (unsigned short*)alloc((size_t)256 * 1024 * 2);
    unsigned short* qk_bf  = (unsigned short*)alloc((size_t)N * 256 * 2);
    unsigned short* emb_bf = (unsigned short*)alloc((size_t)N * 256 * 2);
    unsigned short* QKbuf  = (unsigned short*)alloc((size_t)N * 512 * 2);
    unsigned short* Vtbuf  = (unsigned short*)alloc((size_t)256 * N * 2);
    unsigned short* ctxbuf = (unsigned short*)alloc((size_t)N * 256 * 2);
    float*          ybuf   = (float*)alloc((size_t)N * 256 * 4);
    float*          tgtf   = (float*)alloc((size_t)N * 256 * 4);
    unsigned short* tgtbf  = (unsigned short*)alloc((size_t)N * 256 * 2);
    unsigned short* t2bf   = (unsigned short*)alloc((size_t)N * 256 * 2);
    unsigned short* hbuf   = (unsigned short*)alloc((size_t)N * 1024 * 2);
    float* emb_f32s = (float*)alloc((size_t)N * 256 * 4);
    float* qpos_s   = (float*)alloc((size_t)N * 256 * 4);
    int* permbuf = (int*)alloc((size_t)N * 4);
    int* rankbuf = (int*)alloc((size_t)N * 4);
    int* gidsbuf = (int*)alloc((size_t)N * 4);
    int* offsbuf = (int*)alloc(32 * 4);
    float* Opartbuf = (float*)alloc((size_t)NSPLIT * N * 256 * 4);
    float* lbuf     = (float*)alloc((size_t)NSPLIT * N * 8 * 4);
    (void)ws_size; (void)n_in; (void)out_size;

    const int mt = N >> 6;

    k_sort<<<1, 1024, 0, stream>>>(group_ids, N, permbuf, rankbuf, gidsbuf, offsbuf);
    k_convw<<<1280, 256, 0, stream>>>(in_proj_w, out_proj_w, lin1_w, lin2_w, feat1_w, feat2_w,
                                      wqkv, wout, wlin1, wlin2, wfeat1, wfeat2);
    k_prep<<<N, 256, 0, stream>>>(ref_pts, pred_boxes, scores, out_embed, query_pos, rankbuf,
                                  qk_bf, emb_bf, emb_f32s, qpos_s);

    // fused QKV projection: c0<512 from qk_bf -> QKbuf; c0>=512 from emb_bf -> Vt^T
    k_gemm<EPI_QKV><<<mt * 12, 256, 0, stream>>>(
        qk_bf, emb_bf, wqkv, in_proj_b, nullptr, QKbuf, Vtbuf, N, 768, 256);

    // key-split swapped-QK^T flash attention + combine
    k_attn<<<mt * 8 * NSPLIT, 256, 0, stream>>>(QKbuf, Vtbuf, gidsbuf, offsbuf,
                                                Opartbuf, lbuf, N);
    k_comb<<<N, 256, 0, stream>>>(Opartbuf, lbuf, ctxbuf, N);

    // out-proj + residual(out_embed, sorted f32)
    k_gemm<EPI_RESF32><<<mt * 4, 256, 0, stream>>>(
        ctxbuf, nullptr, wout, out_proj_b, emb_f32s, ybuf, nullptr, N, 256, 256);
    k_ln<0><<<N / 4, 256, 0, stream>>>(ybuf, norm1_w, norm1_b, tgtf, tgtbf, nullptr, nullptr, nullptr);

    k_gemm<EPI_RELUBF><<<mt * 16, 256, 0, stream>>>(
        tgtbf, nullptr, wlin1, lin1_b, nullptr, hbuf, nullptr, N, 1024, 256);
    k_gemm<EPI_RESF32><<<mt * 4, 256, 0, stream>>>(
        hbuf, nullptr, wlin2, lin2_b, tgtf, ybuf, nullptr, N, 256, 1024);
    k_ln<1><<<N / 4, 256, 0, stream>>>(ybuf, norm2_w, norm2_b, nullptr, t2bf, nullptr, nullptr, nullptr);

    k_gemm<EPI_RELUBF><<<mt * 16, 256, 0, stream>>>(
        t2bf, nullptr, wfeat1, feat1_b, nullptr, hbuf, nullptr, N, 1024, 256);
    k_gemm<EPI_RESF32><<<mt * 4, 256, 0, stream>>>(
        hbuf, nullptr, wfeat2, feat2_b, qpos_s, ybuf, nullptr, N, 256, 1024);
    // query_feat = LN(y3); out[perm[p]] = is_pos ? query_feat : query_pos
    k_ln<2><<<N / 4, 256, 0, stream>>>(ybuf, normf_w, normf_b, (float*)d_out, nullptr,
                                       scores, qpos_s, permbuf);
}